// Round 9
// baseline (277.435 us; speedup 1.0000x reference)
//
#include <hip/hip_runtime.h>

typedef unsigned short u16;
typedef unsigned int   u32;
typedef unsigned long long u64;
typedef __bf16 bf16;
typedef float f32x4   __attribute__((ext_vector_type(4)));
typedef float f32x16  __attribute__((ext_vector_type(16)));
typedef bf16  bf16x8  __attribute__((ext_vector_type(8)));

__device__ __forceinline__ float bf2f(u16 u){ return (float)__builtin_bit_cast(bf16,u); }
__device__ __forceinline__ u16   f2bf(float f){ return __builtin_bit_cast(u16,(bf16)f); }
__device__ __forceinline__ u32   pkbf(float a,float b){ return (u32)f2bf(a)|((u32)f2bf(b)<<16); }

#define NROWS 32768

// ---- basis: 8 bf16 slots, NO c6 (folded into B); d2(u)=d1(1-u), d0=w1^3, d3=u^3 ----
__device__ __forceinline__ uint4 basis_pk(float x)
{
  float tp  = __fmaf_rn(x, 2.5f, 5.5f);
  float tpc = fminf(fmaxf(tp, -1.0f), 12.0f);   // out-of-range -> window miss -> zeros
  float fi  = floorf(tpc);
  float uu  = tpc - fi;
  int   i0  = (int)fi;
  float u2 = uu*uu, u3 = u2*uu, w1 = 1.0f-uu, w2 = w1*w1, w3 = w2*w1;
  float d1 = __fmaf_rn(3.0f, u3, __fmaf_rn(-6.0f, u2, 4.0f));
  float d2 = __fmaf_rn(3.0f, w3, __fmaf_rn(-6.0f, w2, 4.0f));
  u64 dpk = (u64)pkbf(w3, d1) | ((u64)pkbf(d2, u3) << 32);
  int ss = i0*16 - 48;
  u64 A  = dpk << (ss & 63);
  u64 Bv = dpk >> ((64-ss) & 63);
  u64 Cv = dpk << ((ss-64) & 63);
  u64 Dv = dpk >> ((-ss) & 63);
  u64 lo = (ss>=0 && ss<64)   ? A  : ((ss<0 && ss>-64) ? Dv : 0ull);
  u64 hi = (ss>=64 && ss<128) ? Cv : ((ss>0 && ss<64)  ? Bv : 0ull);
  uint4 r; r.x=(u32)lo; r.y=(u32)(lo>>32); r.z=(u32)hi; r.w=(u32)(hi>>32);
  return r;
}

__device__ __forceinline__ void expand10(float x, u32& spk, uint4& bpk)
{
  float s = x * (1.0f/(1.0f+__expf(-x)));
  u16 uh = f2bf(s);
  u16 ul = f2bf(s - bf2f(uh));
  spk = (u32)uh | ((u32)ul<<16);
  bpk = basis_pk(x);
}

// ---------------- destination-major weight prep (layouts unchanged from R8) ----------------
struct PrepArgs {
  const float* bw[7]; const float* sw[7]; const float* sc[7];
  u16* w[7];
  int cin[7]; int coutr[7]; int ntsh[7]; int fmt[7];
  u32 elems[7];
};

__global__ __launch_bounds__(256) void prep_kernel(PrepArgs pa)
{
  u32 idx = blockIdx.x*256 + threadIdx.x;
  int L = 0;
  u32 off = idx;
  while (L < 6 && off >= pa.elems[L]) { off -= pa.elems[L]; ++L; }
  int j    = off & 7;
  int lane = (off>>3) & 63;
  u32 tl   = off >> 9;
  int ntsh = pa.ntsh[L];
  u32 kstep = tl >> ntsh;
  int nt   = (int)(tl & ((1u<<ntsh)-1u));
  int i = 0, g = 0, o; bool sil;
  if (pa.fmt[L] == 0){
    o = nt*32 + (lane&31);
    int koct = lane>>5;
    u32 c = kstep/9u; int r = (int)(kstep - c*9u);
    if (r == 0){ i = (int)c*16 + koct*8 + j; sil = true; }
    else       { i = (int)c*16 + (r-1)*2 + koct; g = j; sil = false; }
  } else {
    o = nt*16 + (lane&15);
    int kpos = (lane>>4)*8 + j;
    u32 c = kstep/5u; int r = (int)(kstep - c*5u);
    if (r == 0){ i = (int)c*16 + (kpos>>1); sil = true; }
    else { int kl=(r-1)*32+kpos; i=(int)c*16+(kl>>3); g=kl&7; sil = false; }
  }
  float v = 0.f;
  if (o < pa.coutr[L]) {
    size_t e = (size_t)o*pa.cin[L] + i;
    v = sil ? pa.bw[L][e] : pa.sw[L][e*8+g]*pa.sc[L][e]*0.16666666666666666f;
  }
  pa.w[L][off] = f2bf(v);
}

// ---------------- main layer: in-register expansion, 128-row blocks, 32x32x16 MFMA ----------------
// COUT>=128: 512 thr (8 waves = 2 rg x 4 cg); COUT=64: 256 thr (4 waves = 2 rg x 2 cg).
// A-fragments computed per-lane (basis_pk == fragment); only raw x + silu-bf16 go through LDS.
template<int CIN,int COUT,int IN_MODE,int OUT_MODE>
__global__ __launch_bounds__((COUT>=128)?512:256, 2)
void kan_layer(const void* __restrict__ hin_, const u16* __restrict__ W, void* __restrict__ hout_)
{
  constexpr int CG      = (COUT>=128)?4:2;
  constexpr int THREADS = CG*128;
  constexpr int CFW     = COUT/(CG*32);
  constexpr int NT32    = COUT/32;
  constexpr int NCH     = CIN/16;
  constexpr int TOTK    = NCH*9;
  constexpr int XROW    = 17;           // dw per x row (16 + 1 pad: conflict-free lane-major reads)
  constexpr int SRO     = 12;           // dw per silu row (16 bf16 + pad, keeps b128 16B-aligned)
  constexpr int NLD     = 2048/THREADS; // staging elements per thread
  __shared__ float xs[2][128*XROW];     // 2 x 8704 B
  __shared__ u32  sil[2][128*SRO];      // 2 x 6144 B

  const int b0 = blockIdx.x*128;
  const int tid = threadIdx.x;
  const int wave = tid>>6, lane = tid&63, m32 = lane&31, koct = lane>>5;
  const int rg = wave/CG, cg = wave - rg*CG;

  const u16*   __restrict__ hb = (const u16*)hin_;
  const float* __restrict__ hf = (const float*)hin_;

  f32x16 acc[2][CFW];
#pragma unroll
  for (int a=0;a<2;++a)
#pragma unroll
    for (int c=0;c<CFW;++c)
#pragma unroll
      for (int e=0;e<16;++e) acc[a][c][e] = 0.f;

  bf16x8 bbuf[3][CFW];
  auto loadB = [&](int kstep, bf16x8* dst){
    if (kstep < TOTK){
#pragma unroll
      for (int cf=0; cf<CFW; ++cf)
        dst[cf] = *(const bf16x8*)(W + (((size_t)kstep*NT32 + cg*CFW+cf)*64 + lane)*8);
    }
  };

  float xg[NLD];
  auto loadX = [&](int kc){
#pragma unroll
    for (int t=0;t<NLD;++t){
      int task = t*THREADS+tid, row = task>>4, f = task&15;
      int gi = (b0+row)*CIN + kc*16 + f;
      xg[t] = (IN_MODE==0)? hf[gi] : bf2f(hb[gi]);
    }
  };
  auto stage = [&](int bsel){
#pragma unroll
    for (int t=0;t<NLD;++t){
      int task = t*THREADS+tid, row = task>>4, f = task&15;
      float x = xg[t];
      xs[bsel][row*XROW + f] = x;
      float s = x * __builtin_amdgcn_rcpf(1.0f + __expf(-x));
      ((u16*)&sil[bsel][0])[row*(SRO*2) + f] = f2bf(s);
    }
  };

  loadB(0,bbuf[0]); loadB(1,bbuf[1]);
  loadX(0); stage(0);
  if (NCH>1) loadX(1);
  __syncthreads();

  for (int kc=0; kc<NCH; ++kc){
    const int cs = kc&1;
    const int row0 = rg*64 + m32;       // rfl=0 row; rfl=1 adds 32
#pragma unroll
    for (int r=0; r<9; ++r){
      const int kstep = kc*9 + r;
      loadB(kstep+2, bbuf[2]);
      bf16x8 af[2];
      if (r==0){
#pragma unroll
        for (int rfl=0; rfl<2; ++rfl)
          af[rfl] = __builtin_bit_cast(bf16x8, *(const uint4*)&sil[cs][(row0+rfl*32)*SRO + koct*4]);
      } else {
#pragma unroll
        for (int rfl=0; rfl<2; ++rfl){
          float xv = xs[cs][(row0+rfl*32)*XROW + (r-1)*2 + koct];
          af[rfl] = __builtin_bit_cast(bf16x8, basis_pk(xv));
        }
      }
#pragma unroll
      for (int cf=0; cf<CFW; ++cf)
#pragma unroll
        for (int rfl=0; rfl<2; ++rfl)
          acc[rfl][cf] = __builtin_amdgcn_mfma_f32_32x32x16_bf16(af[rfl], bbuf[0][cf], acc[rfl][cf],0,0,0);
#pragma unroll
      for (int cf=0; cf<CFW; ++cf){ bbuf[0][cf]=bbuf[1][cf]; bbuf[1][cf]=bbuf[2][cf]; }
    }
    if (kc+1 < NCH){ stage((kc+1)&1); if (kc+2 < NCH) loadX(kc+2); }
    __syncthreads();
  }

  // epilogue: 32x32 C/D layout col=lane&31, row=(reg&3)+8*(reg>>2)+4*(lane>>5)  [m74/m101]
#pragma unroll
  for (int rfl=0; rfl<2; ++rfl)
#pragma unroll
    for (int cf=0; cf<CFW; ++cf)
#pragma unroll
      for (int reg=0; reg<16; ++reg){
        int rl  = (reg&3) + 8*(reg>>2) + 4*koct;
        size_t off = (size_t)(b0 + rg*64 + rfl*32 + rl)*COUT + (cg*CFW+cf)*32 + m32;
        if constexpr (OUT_MODE==0) ((float*)hout_)[off] = acc[rfl][cf][reg];
        else                       ((u16*)hout_)[off]   = f2bf(acc[rfl][cf][reg]);
      }
}

// ---------------- fused tail: h2 -> {L3->L4->adv , L5->L6->val} (fmt1 weights, unchanged) ----------------
template<int IN_MODE>
__global__ __launch_bounds__(512,4) void tail_kernel(const void* __restrict__ h2_,
  const u16* __restrict__ W3, const u16* __restrict__ W4,
  const u16* __restrict__ W5, const u16* __restrict__ W6,
  float* __restrict__ out_adv, float* __restrict__ out_val)
{
  constexpr int SROW=20, BROW=68, BOFF=64*20;
  __shared__ u32   Aexp[BOFF + 64*BROW];
  __shared__ float hA[64*65], hV[64*65];

  const int b0 = blockIdx.x*64;
  const int tid = threadIdx.x;
  const int wave = tid>>6, lane = tid&63, m = lane&15, quad = lane>>4;
  const int rg = wave>>2, cg = wave&3;

  const u16*   __restrict__ hb = (const u16*)h2_;
  const float* __restrict__ hf = (const float*)h2_;

  f32x4 a3[2], a5[2];
#pragma unroll
  for (int mt=0;mt<2;++mt){ a3[mt]=(f32x4){0,0,0,0}; a5[mt]=(f32x4){0,0,0,0}; }

  bf16x8 w3b[3], w5b[3];
  auto loadB2 = [&](int kstep, int d){
    if (kstep < 20){
      size_t bi = (((size_t)kstep*4 + cg)*64 + lane)*8;
      w3b[d] = *(const bf16x8*)(W3+bi);
      w5b[d] = *(const bf16x8*)(W5+bi);
    }
  };
  loadB2(0,0); loadB2(1,1);

  float xb[2][2];
  auto loadX = [&](int kc, float* dst){
#pragma unroll
    for (int t=0;t<2;++t){
      int task = t*512+tid, row=task>>4, f=task&15;
      int gi = (b0+row)*64 + kc*16 + f;
      dst[t] = (IN_MODE==0)? hf[gi] : bf2f(hb[gi]);
    }
  };
  loadX(0, xb[0]);

  for (int kc=0; kc<4; ++kc){
    const float* xc = xb[kc&1];
#pragma unroll
    for (int t=0;t<2;++t){
      int task=t*512+tid, row=task>>4, f=task&15;
      u32 spk; uint4 bpk;
      expand10(xc[t], spk, bpk);
      Aexp[row*SROW + f] = spk;
      *(uint4*)&Aexp[BOFF + row*BROW + f*4] = bpk;
    }
    if (kc+1 < 4) loadX(kc+1, xb[(kc+1)&1]);
    __syncthreads();
#pragma unroll
    for (int ks=0; ks<5; ++ks){
      const int kstep = kc*5 + ks;
      loadB2(kstep+2, 2);
      bf16x8 af[2];
#pragma unroll
      for (int mt=0; mt<2; ++mt){
        int row = rg*32 + mt*16 + m;
        af[mt] = (ks==0)
          ? *(const bf16x8*)&Aexp[row*SROW + quad*4]
          : *(const bf16x8*)&Aexp[BOFF + row*BROW + (ks-1)*16 + quad*4];
      }
#pragma unroll
      for (int mt=0; mt<2; ++mt){
        a3[mt] = __builtin_amdgcn_mfma_f32_16x16x32_bf16(af[mt], w3b[0], a3[mt],0,0,0);
        a5[mt] = __builtin_amdgcn_mfma_f32_16x16x32_bf16(af[mt], w5b[0], a5[mt],0,0,0);
      }
      w3b[0]=w3b[1]; w3b[1]=w3b[2]; w5b[0]=w5b[1]; w5b[1]=w5b[2];
    }
    __syncthreads();
  }
#pragma unroll
  for (int mt=0;mt<2;++mt)
#pragma unroll
    for (int r=0;r<4;++r){
      int row = rg*32 + mt*16 + quad*4 + r;
      hA[row*65 + cg*16 + m] = a3[mt][r];
      hV[row*65 + cg*16 + m] = a5[mt][r];
    }
  __syncthreads();

  f32x4 a4[2];
#pragma unroll
  for (int mt=0;mt<2;++mt) a4[mt]=(f32x4){0,0,0,0};
  bf16x8 w4b[3];
  auto loadB4 = [&](int kstep, int d){
    if (kstep < 20) w4b[d] = *(const bf16x8*)(W4 + (((size_t)kstep*4 + cg)*64 + lane)*8);
  };
  loadB4(0,0); loadB4(1,1);
  for (int kc=0; kc<4; ++kc){
#pragma unroll
    for (int t=0;t<2;++t){
      int task=t*512+tid, row=task>>4, f=task&15;
      u32 spk; uint4 bpk;
      expand10(hA[row*65 + kc*16 + f], spk, bpk);
      Aexp[row*SROW + f] = spk;
      *(uint4*)&Aexp[BOFF + row*BROW + f*4] = bpk;
    }
    __syncthreads();
#pragma unroll
    for (int ks=0; ks<5; ++ks){
      loadB4(kc*5+ks+2, 2);
      bf16x8 af[2];
#pragma unroll
      for (int mt=0; mt<2; ++mt){
        int row = rg*32 + mt*16 + m;
        af[mt] = (ks==0)
          ? *(const bf16x8*)&Aexp[row*SROW + quad*4]
          : *(const bf16x8*)&Aexp[BOFF + row*BROW + (ks-1)*16 + quad*4];
      }
#pragma unroll
      for (int mt=0; mt<2; ++mt)
        a4[mt] = __builtin_amdgcn_mfma_f32_16x16x32_bf16(af[mt], w4b[0], a4[mt],0,0,0);
      w4b[0]=w4b[1]; w4b[1]=w4b[2];
    }
    __syncthreads();
  }
  {
    int col = cg*16 + m;
    if (col < 18){
#pragma unroll
      for (int mt=0;mt<2;++mt)
#pragma unroll
        for (int r=0;r<4;++r)
          out_adv[(size_t)(b0 + rg*32 + mt*16 + quad*4 + r)*18 + col] = a4[mt][r];
    }
  }

  f32x4 a6[2];
#pragma unroll
  for (int mt=0;mt<2;++mt) a6[mt]=(f32x4){0,0,0,0};
  bf16x8 w6b[3];
  auto loadB6 = [&](int kstep, int d){
    if (kstep < 20) w6b[d] = *(const bf16x8*)(W6 + (((size_t)kstep*4 + cg)*64 + lane)*8);
  };
  loadB6(0,0); loadB6(1,1);
  for (int kc=0; kc<4; ++kc){
#pragma unroll
    for (int t=0;t<2;++t){
      int task=t*512+tid, row=task>>4, f=task&15;
      u32 spk; uint4 bpk;
      expand10(hV[row*65 + kc*16 + f], spk, bpk);
      Aexp[row*SROW + f] = spk;
      *(uint4*)&Aexp[BOFF + row*BROW + f*4] = bpk;
    }
    __syncthreads();
#pragma unroll
    for (int ks=0; ks<5; ++ks){
      loadB6(kc*5+ks+2, 2);
      bf16x8 af[2];
#pragma unroll
      for (int mt=0; mt<2; ++mt){
        int row = rg*32 + mt*16 + m;
        af[mt] = (ks==0)
          ? *(const bf16x8*)&Aexp[row*SROW + quad*4]
          : *(const bf16x8*)&Aexp[BOFF + row*BROW + (ks-1)*16 + quad*4];
      }
#pragma unroll
      for (int mt=0; mt<2; ++mt)
        a6[mt] = __builtin_amdgcn_mfma_f32_16x16x32_bf16(af[mt], w6b[0], a6[mt],0,0,0);
      w6b[0]=w6b[1]; w6b[1]=w6b[2];
    }
    __syncthreads();
  }
  if (cg==0 && m==0){
#pragma unroll
    for (int mt=0;mt<2;++mt)
#pragma unroll
      for (int r=0;r<4;++r)
        out_val[b0 + rg*32 + mt*16 + quad*4 + r] = a6[mt][r];
  }
}

extern "C" void kernel_launch(void* const* d_in, const int* in_sizes, int n_in,
                              void* d_out, int out_size, void* d_ws, size_t ws_size,
                              hipStream_t stream)
{
  (void)in_sizes; (void)n_in; (void)out_size;
  char* ws = (char*)d_ws;

  const size_t wbytes[7] = {589824u, 1179648u, 294912u, 81920u, 81920u, 81920u, 81920u};
  const bool midf32 = ws_size >= 77889536u;

  u16* W[7];
  char *h0, *h1, *h2;
  if (midf32) {
    h0 = ws;                       // 32768x256 f32
    h1 = h0 + 33554432u;
    h2 = h1 + 33554432u;           // 32768x64 f32
    size_t off = 75497472u;
    for (int l=0;l<7;++l){ W[l] = (u16*)(ws+off); off += wbytes[l]; }
  } else {
    h0 = ws;                       // bf16 fallback
    h1 = h0 + 16777216u;
    h2 = h1 + 16777216u;
    size_t off = 37748736u;
    for (int l=0;l<7;++l){ W[l] = (u16*)(ws+off); off += wbytes[l]; }
  }

  PrepArgs pa;
  const int cins[7]   = {128,256,256,64,64,64,64};
  const int coutr[7]  = {256,256,64,64,18,64,1};
  const int ntsh[7]   = {3,3,1,2,2,2,2};     // fmt0: log2(COUT/32); fmt1: log2(4)
  const int fmts[7]   = {0,0,0,1,1,1,1};
  const u32 elems[7]  = {294912u,589824u,147456u,40960u,40960u,40960u,40960u};
  for (int l=0;l<7;++l){
    pa.bw[l] = (const float*)d_in[1+3*l];
    pa.sw[l] = (const float*)d_in[2+3*l];
    pa.sc[l] = (const float*)d_in[3+3*l];
    pa.w[l]  = W[l];
    pa.cin[l]=cins[l]; pa.coutr[l]=coutr[l]; pa.ntsh[l]=ntsh[l]; pa.fmt[l]=fmts[l];
    pa.elems[l]=elems[l];
  }
  prep_kernel<<<4672, 256, 0, stream>>>(pa);

  dim3 gmain(NROWS/128), gtail(NROWS/64);
  float* out_adv = (float*)d_out;
  float* out_val = (float*)d_out + (size_t)NROWS*18;
  if (midf32) {
    kan_layer<128,256,0,0><<<gmain,512,0,stream>>>(d_in[0], W[0], h0);
    kan_layer<256,256,0,0><<<gmain,512,0,stream>>>(h0, W[1], h1);
    kan_layer<256, 64,0,0><<<gmain,256,0,stream>>>(h1, W[2], h2);
    tail_kernel<0><<<gtail,512,0,stream>>>(h2, W[3], W[4], W[5], W[6], out_adv, out_val);
  } else {
    kan_layer<128,256,0,1><<<gmain,512,0,stream>>>(d_in[0], W[0], h0);
    kan_layer<256,256,1,1><<<gmain,512,0,stream>>>(h0, W[1], h1);
    kan_layer<256, 64,1,1><<<gmain,256,0,stream>>>(h1, W[2], h2);
    tail_kernel<1><<<gtail,512,0,stream>>>(h2, W[3], W[4], W[5], W[6], out_adv, out_val);
  }
}

// Round 10
// 246.885 us; speedup vs baseline: 1.1237x; 1.1237x over previous
//
#include <hip/hip_runtime.h>

typedef unsigned short u16;
typedef unsigned int   u32;
typedef unsigned long long u64;
typedef __bf16 bf16;
typedef float f32x4   __attribute__((ext_vector_type(4)));
typedef float f32x16  __attribute__((ext_vector_type(16)));
typedef bf16  bf16x8  __attribute__((ext_vector_type(8)));

__device__ __forceinline__ float bf2f(u16 u){ return (float)__builtin_bit_cast(bf16,u); }
__device__ __forceinline__ u16   f2bf(float f){ return __builtin_bit_cast(u16,(bf16)f); }
__device__ __forceinline__ u32   pkbf(float a,float b){ return (u32)f2bf(a)|((u32)f2bf(b)<<16); }

#define NROWS 32768

// ---- basis: 8 bf16 slots, NO c6 (folded into B); d2(u)=d1(1-u), d0=w1^3, d3=u^3 ----
__device__ __forceinline__ uint4 basis_pk(float x)
{
  float tp  = __fmaf_rn(x, 2.5f, 5.5f);
  float tpc = fminf(fmaxf(tp, -1.0f), 12.0f);   // out-of-range -> window miss -> zeros
  float fi  = floorf(tpc);
  float uu  = tpc - fi;
  int   i0  = (int)fi;
  float u2 = uu*uu, u3 = u2*uu, w1 = 1.0f-uu, w2 = w1*w1, w3 = w2*w1;
  float d1 = __fmaf_rn(3.0f, u3, __fmaf_rn(-6.0f, u2, 4.0f));
  float d2 = __fmaf_rn(3.0f, w3, __fmaf_rn(-6.0f, w2, 4.0f));
  u64 dpk = (u64)pkbf(w3, d1) | ((u64)pkbf(d2, u3) << 32);
  int ss = i0*16 - 48;
  u64 A  = dpk << (ss & 63);
  u64 Bv = dpk >> ((64-ss) & 63);
  u64 Cv = dpk << ((ss-64) & 63);
  u64 Dv = dpk >> ((-ss) & 63);
  u64 lo = (ss>=0 && ss<64)   ? A  : ((ss<0 && ss>-64) ? Dv : 0ull);
  u64 hi = (ss>=64 && ss<128) ? Cv : ((ss>0 && ss<64)  ? Bv : 0ull);
  uint4 r; r.x=(u32)lo; r.y=(u32)(lo>>32); r.z=(u32)hi; r.w=(u32)(hi>>32);
  return r;
}

__device__ __forceinline__ void expand10(float x, u32& spk, uint4& bpk)
{
  float s = x * (1.0f/(1.0f+__expf(-x)));
  u16 uh = f2bf(s);
  u16 ul = f2bf(s - bf2f(uh));
  spk = (u32)uh | ((u32)ul<<16);
  bpk = basis_pk(x);
}

// ---------------- destination-major weight prep (layouts unchanged from R8/R9) ----------------
struct PrepArgs {
  const float* bw[7]; const float* sw[7]; const float* sc[7];
  u16* w[7];
  int cin[7]; int coutr[7]; int ntsh[7]; int fmt[7];
  u32 elems[7];
};

__global__ __launch_bounds__(256) void prep_kernel(PrepArgs pa)
{
  u32 idx = blockIdx.x*256 + threadIdx.x;
  int L = 0;
  u32 off = idx;
  while (L < 6 && off >= pa.elems[L]) { off -= pa.elems[L]; ++L; }
  int j    = off & 7;
  int lane = (off>>3) & 63;
  u32 tl   = off >> 9;
  int ntsh = pa.ntsh[L];
  u32 kstep = tl >> ntsh;
  int nt   = (int)(tl & ((1u<<ntsh)-1u));
  int i = 0, g = 0, o; bool sil;
  if (pa.fmt[L] == 0){
    o = nt*32 + (lane&31);
    int koct = lane>>5;
    u32 c = kstep/9u; int r = (int)(kstep - c*9u);
    if (r == 0){ i = (int)c*16 + koct*8 + j; sil = true; }
    else       { i = (int)c*16 + (r-1)*2 + koct; g = j; sil = false; }
  } else {
    o = nt*16 + (lane&15);
    int kpos = (lane>>4)*8 + j;
    u32 c = kstep/5u; int r = (int)(kstep - c*5u);
    if (r == 0){ i = (int)c*16 + (kpos>>1); sil = true; }
    else { int kl=(r-1)*32+kpos; i=(int)c*16+(kl>>3); g=kl&7; sil = false; }
  }
  float v = 0.f;
  if (o < pa.coutr[L]) {
    size_t e = (size_t)o*pa.cin[L] + i;
    v = sil ? pa.bw[L][e] : pa.sw[L][e*8+g]*pa.sc[L][e]*0.16666666666666666f;
  }
  pa.w[L][off] = f2bf(v);
}

// ---------------- main layer: 512 thr, 64-row blocks, 32x32x16 MFMA ----------------
// 8 waves = 2 rg (32-row groups) x 4 cg (col groups); LDS-materialized expansion (dup=1 VALU);
// deep register B-prefetch (bf16x8 = 4 VGPR) to cover L2 latency.
template<int CIN,int COUT,int IN_MODE,int OUT_MODE>
__global__ __launch_bounds__(512,4)
void kan_layer(const void* __restrict__ hin_, const u16* __restrict__ W, void* __restrict__ hout_)
{
  constexpr int NT32  = COUT/32;
  constexpr int CFW   = (NT32>=4)? NT32/4 : 1;
  constexpr int DEPTH = (CFW>=2)? 6 : 8;
  constexpr int NCH   = CIN/16;
  constexpr int TOTK  = NCH*9;
  constexpr int SROW=12, BROW=68, BOFF=64*SROW;   // R8-verified conflict-free strides
  constexpr int CHUNK = BOFF + 64*BROW;           // 5120 dw = 20480 B
  __shared__ alignas(16) u32 buf[2][CHUNK];       // 40960 B -> 2 blocks/CU

  const int b0 = blockIdx.x*64;
  const int tid = threadIdx.x;
  const int wave = tid>>6, lane = tid&63, m32 = lane&31, koct = lane>>5;
  const int rg = wave>>2, cgw = wave&3;
  const int ctbase = (cgw*CFW) & (NT32-1);
  const bool wstore = (cgw*CFW) < NT32;

  const u16*   __restrict__ hb = (const u16*)hin_;
  const float* __restrict__ hf = (const float*)hin_;

  f32x16 acc[CFW];
#pragma unroll
  for (int c=0;c<CFW;++c)
#pragma unroll
    for (int e=0;e<16;++e) acc[c][e] = 0.f;

  bf16x8 bbuf[DEPTH][CFW];
  auto loadB = [&](int kstep, bf16x8* dst){
    if (kstep < TOTK){
#pragma unroll
      for (int cf=0; cf<CFW; ++cf)
        dst[cf] = *(const bf16x8*)(W + (((size_t)kstep*NT32 + ctbase+cf)*64 + lane)*8);
    }
  };
#pragma unroll
  for (int d=0; d<DEPTH-1; ++d) loadB(d, bbuf[d]);

  float xb[2][2];
  auto loadX = [&](int kc, float* dst){
#pragma unroll
    for (int t=0;t<2;++t){
      int task = t*512+tid, row = task>>4, f = task&15;
      int gi = (b0+row)*CIN + kc*16 + f;
      dst[t] = (IN_MODE==0)? hf[gi] : bf2f(hb[gi]);
    }
  };
  auto stage = [&](const float* xc, u32* dstb){
#pragma unroll
    for (int t=0;t<2;++t){
      int task = t*512+tid, row = task>>4, f = task&15;
      float x = xc[t];
      float s = x * __builtin_amdgcn_rcpf(1.0f + __expf(-x));
      ((u16*)dstb)[row*(SROW*2) + f] = f2bf(s);
      *(uint4*)&dstb[BOFF + row*BROW + f*4] = basis_pk(x);
    }
  };

  loadX(0, xb[0]);
  stage(xb[0], buf[0]);
  if (NCH>1) loadX(1, xb[1]);
  __syncthreads();

  for (int kc=0; kc<NCH; ++kc){
    u32* cur = buf[kc&1];
    u32* nxt = buf[(kc+1)&1];
    if (kc+1 < NCH) stage(xb[(kc+1)&1], nxt);
    if (kc+2 < NCH) loadX(kc+2, xb[kc&1]);
    const int row = rg*32 + m32;
#pragma unroll
    for (int r=0; r<9; ++r){
      const int kstep = kc*9 + r;
      loadB(kstep+DEPTH-1, bbuf[DEPTH-1]);
      bf16x8 af;
      if (r==0) af = __builtin_bit_cast(bf16x8, *(const uint4*)&cur[row*SROW + koct*4]);
      else      af = __builtin_bit_cast(bf16x8, *(const uint4*)&cur[BOFF + row*BROW + ((r-1)*2+koct)*4]);
#pragma unroll
      for (int cf=0; cf<CFW; ++cf)
        acc[cf] = __builtin_amdgcn_mfma_f32_32x32x16_bf16(af, bbuf[0][cf], acc[cf],0,0,0);
#pragma unroll
      for (int d=0; d<DEPTH-1; ++d)
#pragma unroll
        for (int cf=0; cf<CFW; ++cf) bbuf[d][cf] = bbuf[d+1][cf];
    }
    __syncthreads();
  }

  // epilogue: 32x32 C/D layout col=lane&31, row=(reg&3)+8*(reg>>2)+4*(lane>>5)  [m74/m101]
  if (wstore){
#pragma unroll
    for (int cf=0; cf<CFW; ++cf)
#pragma unroll
      for (int reg=0; reg<16; ++reg){
        int rl  = (reg&3) + 8*(reg>>2) + 4*koct;
        size_t off = (size_t)(b0 + rg*32 + rl)*COUT + (ctbase+cf)*32 + m32;
        if constexpr (OUT_MODE==0) ((float*)hout_)[off] = acc[cf][reg];
        else                       ((u16*)hout_)[off]   = f2bf(acc[cf][reg]);
      }
  }
}

// ---------------- fused tail: h2 -> {L3->L4->adv , L5->L6->val} (fmt1 weights, unchanged) ----------------
template<int IN_MODE>
__global__ __launch_bounds__(512,4) void tail_kernel(const void* __restrict__ h2_,
  const u16* __restrict__ W3, const u16* __restrict__ W4,
  const u16* __restrict__ W5, const u16* __restrict__ W6,
  float* __restrict__ out_adv, float* __restrict__ out_val)
{
  constexpr int SROW=20, BROW=68, BOFF=64*20;
  __shared__ u32   Aexp[BOFF + 64*BROW];
  __shared__ float hA[64*65], hV[64*65];

  const int b0 = blockIdx.x*64;
  const int tid = threadIdx.x;
  const int wave = tid>>6, lane = tid&63, m = lane&15, quad = lane>>4;
  const int rg = wave>>2, cg = wave&3;

  const u16*   __restrict__ hb = (const u16*)h2_;
  const float* __restrict__ hf = (const float*)h2_;

  f32x4 a3[2], a5[2];
#pragma unroll
  for (int mt=0;mt<2;++mt){ a3[mt]=(f32x4){0,0,0,0}; a5[mt]=(f32x4){0,0,0,0}; }

  bf16x8 w3b[3], w5b[3];
  auto loadB2 = [&](int kstep, int d){
    if (kstep < 20){
      size_t bi = (((size_t)kstep*4 + cg)*64 + lane)*8;
      w3b[d] = *(const bf16x8*)(W3+bi);
      w5b[d] = *(const bf16x8*)(W5+bi);
    }
  };
  loadB2(0,0); loadB2(1,1);

  float xb[2][2];
  auto loadX = [&](int kc, float* dst){
#pragma unroll
    for (int t=0;t<2;++t){
      int task = t*512+tid, row=task>>4, f=task&15;
      int gi = (b0+row)*64 + kc*16 + f;
      dst[t] = (IN_MODE==0)? hf[gi] : bf2f(hb[gi]);
    }
  };
  loadX(0, xb[0]);

  for (int kc=0; kc<4; ++kc){
    const float* xc = xb[kc&1];
#pragma unroll
    for (int t=0;t<2;++t){
      int task=t*512+tid, row=task>>4, f=task&15;
      u32 spk; uint4 bpk;
      expand10(xc[t], spk, bpk);
      Aexp[row*SROW + f] = spk;
      *(uint4*)&Aexp[BOFF + row*BROW + f*4] = bpk;
    }
    if (kc+1 < 4) loadX(kc+1, xb[(kc+1)&1]);
    __syncthreads();
#pragma unroll
    for (int ks=0; ks<5; ++ks){
      const int kstep = kc*5 + ks;
      loadB2(kstep+2, 2);
      bf16x8 af[2];
#pragma unroll
      for (int mt=0; mt<2; ++mt){
        int row = rg*32 + mt*16 + m;
        af[mt] = (ks==0)
          ? *(const bf16x8*)&Aexp[row*SROW + quad*4]
          : *(const bf16x8*)&Aexp[BOFF + row*BROW + (ks-1)*16 + quad*4];
      }
#pragma unroll
      for (int mt=0; mt<2; ++mt){
        a3[mt] = __builtin_amdgcn_mfma_f32_16x16x32_bf16(af[mt], w3b[0], a3[mt],0,0,0);
        a5[mt] = __builtin_amdgcn_mfma_f32_16x16x32_bf16(af[mt], w5b[0], a5[mt],0,0,0);
      }
      w3b[0]=w3b[1]; w3b[1]=w3b[2]; w5b[0]=w5b[1]; w5b[1]=w5b[2];
    }
    __syncthreads();
  }
#pragma unroll
  for (int mt=0;mt<2;++mt)
#pragma unroll
    for (int r=0;r<4;++r){
      int row = rg*32 + mt*16 + quad*4 + r;
      hA[row*65 + cg*16 + m] = a3[mt][r];
      hV[row*65 + cg*16 + m] = a5[mt][r];
    }
  __syncthreads();

  f32x4 a4[2];
#pragma unroll
  for (int mt=0;mt<2;++mt) a4[mt]=(f32x4){0,0,0,0};
  bf16x8 w4b[3];
  auto loadB4 = [&](int kstep, int d){
    if (kstep < 20) w4b[d] = *(const bf16x8*)(W4 + (((size_t)kstep*4 + cg)*64 + lane)*8);
  };
  loadB4(0,0); loadB4(1,1);
  for (int kc=0; kc<4; ++kc){
#pragma unroll
    for (int t=0;t<2;++t){
      int task=t*512+tid, row=task>>4, f=task&15;
      u32 spk; uint4 bpk;
      expand10(hA[row*65 + kc*16 + f], spk, bpk);
      Aexp[row*SROW + f] = spk;
      *(uint4*)&Aexp[BOFF + row*BROW + f*4] = bpk;
    }
    __syncthreads();
#pragma unroll
    for (int ks=0; ks<5; ++ks){
      loadB4(kc*5+ks+2, 2);
      bf16x8 af[2];
#pragma unroll
      for (int mt=0; mt<2; ++mt){
        int row = rg*32 + mt*16 + m;
        af[mt] = (ks==0)
          ? *(const bf16x8*)&Aexp[row*SROW + quad*4]
          : *(const bf16x8*)&Aexp[BOFF + row*BROW + (ks-1)*16 + quad*4];
      }
#pragma unroll
      for (int mt=0; mt<2; ++mt)
        a4[mt] = __builtin_amdgcn_mfma_f32_16x16x32_bf16(af[mt], w4b[0], a4[mt],0,0,0);
      w4b[0]=w4b[1]; w4b[1]=w4b[2];
    }
    __syncthreads();
  }
  {
    int col = cg*16 + m;
    if (col < 18){
#pragma unroll
      for (int mt=0;mt<2;++mt)
#pragma unroll
        for (int r=0;r<4;++r)
          out_adv[(size_t)(b0 + rg*32 + mt*16 + quad*4 + r)*18 + col] = a4[mt][r];
    }
  }

  f32x4 a6[2];
#pragma unroll
  for (int mt=0;mt<2;++mt) a6[mt]=(f32x4){0,0,0,0};
  bf16x8 w6b[3];
  auto loadB6 = [&](int kstep, int d){
    if (kstep < 20) w6b[d] = *(const bf16x8*)(W6 + (((size_t)kstep*4 + cg)*64 + lane)*8);
  };
  loadB6(0,0); loadB6(1,1);
  for (int kc=0; kc<4; ++kc){
#pragma unroll
    for (int t=0;t<2;++t){
      int task=t*512+tid, row=task>>4, f=task&15;
      u32 spk; uint4 bpk;
      expand10(hV[row*65 + kc*16 + f], spk, bpk);
      Aexp[row*SROW + f] = spk;
      *(uint4*)&Aexp[BOFF + row*BROW + f*4] = bpk;
    }
    __syncthreads();
#pragma unroll
    for (int ks=0; ks<5; ++ks){
      loadB6(kc*5+ks+2, 2);
      bf16x8 af[2];
#pragma unroll
      for (int mt=0; mt<2; ++mt){
        int row = rg*32 + mt*16 + m;
        af[mt] = (ks==0)
          ? *(const bf16x8*)&Aexp[row*SROW + quad*4]
          : *(const bf16x8*)&Aexp[BOFF + row*BROW + (ks-1)*16 + quad*4];
      }
#pragma unroll
      for (int mt=0; mt<2; ++mt)
        a6[mt] = __builtin_amdgcn_mfma_f32_16x16x32_bf16(af[mt], w6b[0], a6[mt],0,0,0);
      w6b[0]=w6b[1]; w6b[1]=w6b[2];
    }
    __syncthreads();
  }
  if (cg==0 && m==0){
#pragma unroll
    for (int mt=0;mt<2;++mt)
#pragma unroll
      for (int r=0;r<4;++r)
        out_val[b0 + rg*32 + mt*16 + quad*4 + r] = a6[mt][r];
  }
}

extern "C" void kernel_launch(void* const* d_in, const int* in_sizes, int n_in,
                              void* d_out, int out_size, void* d_ws, size_t ws_size,
                              hipStream_t stream)
{
  (void)in_sizes; (void)n_in; (void)out_size;
  char* ws = (char*)d_ws;

  const size_t wbytes[7] = {589824u, 1179648u, 294912u, 81920u, 81920u, 81920u, 81920u};
  const bool midf32 = ws_size >= 77889536u;

  u16* W[7];
  char *h0, *h1, *h2;
  if (midf32) {
    h0 = ws;                       // 32768x256 f32
    h1 = h0 + 33554432u;
    h2 = h1 + 33554432u;           // 32768x64 f32
    size_t off = 75497472u;
    for (int l=0;l<7;++l){ W[l] = (u16*)(ws+off); off += wbytes[l]; }
  } else {
    h0 = ws;                       // bf16 fallback
    h1 = h0 + 16777216u;
    h2 = h1 + 16777216u;
    size_t off = 37748736u;
    for (int l=0;l<7;++l){ W[l] = (u16*)(ws+off); off += wbytes[l]; }
  }

  PrepArgs pa;
  const int cins[7]   = {128,256,256,64,64,64,64};
  const int coutr[7]  = {256,256,64,64,18,64,1};
  const int ntsh[7]   = {3,3,1,2,2,2,2};     // fmt0: log2(COUT/32); fmt1: log2(4)
  const int fmts[7]   = {0,0,0,1,1,1,1};
  const u32 elems[7]  = {294912u,589824u,147456u,40960u,40960u,40960u,40960u};
  for (int l=0;l<7;++l){
    pa.bw[l] = (const float*)d_in[1+3*l];
    pa.sw[l] = (const float*)d_in[2+3*l];
    pa.sc[l] = (const float*)d_in[3+3*l];
    pa.w[l]  = W[l];
    pa.cin[l]=cins[l]; pa.coutr[l]=coutr[l]; pa.ntsh[l]=ntsh[l]; pa.fmt[l]=fmts[l];
    pa.elems[l]=elems[l];
  }
  prep_kernel<<<4672, 256, 0, stream>>>(pa);

  dim3 g(NROWS/64);
  float* out_adv = (float*)d_out;
  float* out_val = (float*)d_out + (size_t)NROWS*18;
  if (midf32) {
    kan_layer<128,256,0,0><<<g,512,0,stream>>>(d_in[0], W[0], h0);
    kan_layer<256,256,0,0><<<g,512,0,stream>>>(h0, W[1], h1);
    kan_layer<256, 64,0,0><<<g,512,0,stream>>>(h1, W[2], h2);
    tail_kernel<0><<<g,512,0,stream>>>(h2, W[3], W[4], W[5], W[6], out_adv, out_val);
  } else {
    kan_layer<128,256,0,1><<<g,512,0,stream>>>(d_in[0], W[0], h0);
    kan_layer<256,256,1,1><<<g,512,0,stream>>>(h0, W[1], h1);
    kan_layer<256, 64,1,1><<<g,512,0,stream>>>(h1, W[2], h2);
    tail_kernel<1><<<g,512,0,stream>>>(h2, W[3], W[4], W[5], W[6], out_adv, out_val);
  }
}